// Round 6
// baseline (138.305 us; speedup 1.0000x reference)
//
#include <hip/hip_runtime.h>
#include <hip/hip_bf16.h>

#define NPTS 384
#define NN (NPTS * NPTS)
#define DIMS 256
#define IT 4                  // i's per main-kernel block
#define NZI (NPTS / IT)       // 96 i-chunks

// ---------------------------------------------------------------------------
// Kernel 1: fused Gram + derive, one 32x32 tile per block.
// Block (16,16,4): z-slice kc computes a K=64 chunk of the 2x2 micro-tile
// (288 blocks x 16 waves = 4608 waves ~4.5/SIMD), LDS-reduce, epilogue.
// Outputs per matrix (NO G matrix — reconstructed in main from h + diag):
//   UH[i][j] = {u, h} = {1/max(||e_i-e_j||,eps) (0 on diag), G_ii/2 - G_ij}
//   HD[i]    = G_ii/2           (written by diagonal blocks only)
// ---------------------------------------------------------------------------
__global__ __launch_bounds__(1024) void gram_fused_kernel(
        const float* __restrict__ Es, const float* __restrict__ Et,
        float2* __restrict__ UHs, float2* __restrict__ UHt,
        float* __restrict__ HDs, float* __restrict__ HDt,
        float* __restrict__ out) {
    const int z = blockIdx.z;
    const float* __restrict__ E  = z ? Et : Es;
    float2*      __restrict__ UH = z ? UHt : UHs;
    float*       __restrict__ HD = z ? HDt : HDs;

    const int tx = threadIdx.x;          // 0..15
    const int ty = threadIdx.y;          // 0..15
    const int kc = threadIdx.z;          // 0..3 (K chunk)
    const int t  = kc * 256 + ty * 16 + tx;
    const int i0 = blockIdx.x * 32;
    const int j0 = blockIdx.y * 32;

    if (blockIdx.x == 0 && blockIdx.y == 0 && z == 0 && t == 0) out[0] = 0.0f;

    __shared__ float sn[64];
    __shared__ float red[4][1024];

    // --- row squared-norms: 64 rows (32 i-side, 32 j-side), 16 thr/row ---
    {
        const int r = t >> 4;            // 0..63
        const int p = t & 15;
        const int row = (r < 32) ? (i0 + r) : (j0 + r - 32);
        const float4* __restrict__ src = (const float4*)(E + row * DIMS) + p * 4;
        float s = 0.f;
#pragma unroll
        for (int q = 0; q < 4; q++) {
            const float4 v = src[q];
            s += v.x * v.x + v.y * v.y + v.z * v.z + v.w * v.w;
        }
        s += __shfl_xor(s, 1, 64);
        s += __shfl_xor(s, 2, 64);
        s += __shfl_xor(s, 4, 64);
        s += __shfl_xor(s, 8, 64);
        if (p == 0) sn[r] = s;
    }

    // --- Gram 2x2 micro-tile over this slice's K=64 chunk ---
    const int i = i0 + 2 * ty;
    const int j = j0 + 2 * tx;
    const float4* __restrict__ a0 = (const float4*)(E + i * DIMS + kc * 64);
    const float4* __restrict__ a1 = (const float4*)(E + (i + 1) * DIMS + kc * 64);
    const float4* __restrict__ b0 = (const float4*)(E + j * DIMS + kc * 64);
    const float4* __restrict__ b1 = (const float4*)(E + (j + 1) * DIMS + kc * 64);

    float g00 = 0.f, g01 = 0.f, g10 = 0.f, g11 = 0.f;
#pragma unroll 4
    for (int k = 0; k < 16; k++) {
        const float4 av0 = a0[k], av1 = a1[k], bv0 = b0[k], bv1 = b1[k];
        g00 = fmaf(av0.x, bv0.x, g00); g00 = fmaf(av0.y, bv0.y, g00);
        g00 = fmaf(av0.z, bv0.z, g00); g00 = fmaf(av0.w, bv0.w, g00);
        g01 = fmaf(av0.x, bv1.x, g01); g01 = fmaf(av0.y, bv1.y, g01);
        g01 = fmaf(av0.z, bv1.z, g01); g01 = fmaf(av0.w, bv1.w, g01);
        g10 = fmaf(av1.x, bv0.x, g10); g10 = fmaf(av1.y, bv0.y, g10);
        g10 = fmaf(av1.z, bv0.z, g10); g10 = fmaf(av1.w, bv0.w, g10);
        g11 = fmaf(av1.x, bv1.x, g11); g11 = fmaf(av1.y, bv1.y, g11);
        g11 = fmaf(av1.z, bv1.z, g11); g11 = fmaf(av1.w, bv1.w, g11);
    }

    const int t2 = ty * 16 + tx;
    *(float4*)&red[kc][t2 * 4] = make_float4(g00, g01, g10, g11);
    __syncthreads();

    if (kc == 0) {
        const float4 r0 = *(const float4*)&red[0][t2 * 4];
        const float4 r1 = *(const float4*)&red[1][t2 * 4];
        const float4 r2 = *(const float4*)&red[2][t2 * 4];
        const float4 r3 = *(const float4*)&red[3][t2 * 4];
        const float g[2][2] = {{r0.x + r1.x + r2.x + r3.x, r0.y + r1.y + r2.y + r3.y},
                               {r0.z + r1.z + r2.z + r3.z, r0.w + r1.w + r2.w + r3.w}};
        const float si[2] = {sn[2 * ty], sn[2 * ty + 1]};
        const float sj[2] = {sn[32 + 2 * tx], sn[32 + 2 * tx + 1]};

#pragma unroll
        for (int r = 0; r < 2; r++) {
            const int ii = i + r;
            float uh[4];
#pragma unroll
            for (int c = 0; c < 2; c++) {
                const int jj = j + c;
                const float gv = g[r][c];
                const float v  = si[r] + sj[c] - 2.0f * gv;
                const float n  = sqrtf(fmaxf(v, 0.0f));
                uh[2 * c]     = (ii == jj) ? 0.0f : (1.0f / fmaxf(n, 1e-12f));
                uh[2 * c + 1] = 0.5f * si[r] - gv;
            }
            *(float4*)(UH + ii * NPTS + j) = make_float4(uh[0], uh[1], uh[2], uh[3]);
        }
        // diagonal blocks write HD[i] = G_ii/2 (= sn/2)
        if (blockIdx.x == blockIdx.y && t2 < 32) HD[i0 + t2] = 0.5f * sn[t2];
    }
}

// ---------------------------------------------------------------------------
// Kernel 2: main reduction over triangular (jt<=kt) 64x64 tile set.
//   G_jk = HD[j] - h_jk   (reconstructed; diag exact)
//   angle_ijk = u_ij * u_ik * (G_jk + h_ij + h_ik)
//   smooth_l1(d) = 0.5 * med3(d*d, 2|d|-1, 1)
// 16x16 threads, 4x4 micro-tile, IT=4 i's per block -> 2016 blocks for TLP
// under the post-poison writeback drain. No explicit prefetch (reg pressure).
// ---------------------------------------------------------------------------
__global__ __launch_bounds__(256) void rkd_main_kernel(
        const float2* __restrict__ UHs, const float2* __restrict__ UHt,
        const float* __restrict__ HDs, const float* __restrict__ HDt,
        float* __restrict__ out) {
    const int tlin = blockIdx.x;
    const int kt = (int)((sqrtf(8.0f * (float)tlin + 1.0f) - 1.0f) * 0.5f);
    const int jt = tlin - (kt * (kt + 1)) / 2;

    const int tx = threadIdx.x;    // k-dim
    const int ty = threadIdx.y;    // j-dim
    const int jb = jt * 64 + 4 * ty;
    const int kb = kt * 64 + 4 * tx;
    const int ibase = blockIdx.y * IT;

    // tile constants: cs[a][b] = G_jk (s), ct[a][b] = G_jk (t)
    float cs[4][4], ct[4][4];
#pragma unroll
    for (int a = 0; a < 4; a++) {
        const float4* rs = (const float4*)(UHs + (jb + a) * NPTS + kb);
        const float4* rt = (const float4*)(UHt + (jb + a) * NPTS + kb);
        const float4 s0 = rs[0], s1 = rs[1];
        const float4 t0 = rt[0], t1 = rt[1];
        const float hds = HDs[jb + a], hdt = HDt[jb + a];
        cs[a][0] = hds - s0.y; cs[a][1] = hds - s0.w;
        cs[a][2] = hds - s1.y; cs[a][3] = hds - s1.w;
        ct[a][0] = hdt - t0.y; ct[a][1] = hdt - t0.w;
        ct[a][2] = hdt - t1.y; ct[a][3] = hdt - t1.w;
    }

    const float4* __restrict__ pjs = (const float4*)(UHs + (size_t)ibase * NPTS + jb);
    const float4* __restrict__ pjt = (const float4*)(UHt + (size_t)ibase * NPTS + jb);
    const float4* __restrict__ pks = (const float4*)(UHs + (size_t)ibase * NPTS + kb);
    const float4* __restrict__ pkt = (const float4*)(UHt + (size_t)ibase * NPTS + kb);

    const bool offd = (jt != kt);
    float wh[4][4];
#pragma unroll
    for (int a = 0; a < 4; a++)
#pragma unroll
        for (int b = 0; b < 4; b++) {
            const int jj = jb + a, kk = kb + b;
            wh[a][b] = (kk > jj) ? 1.0f : ((kk == jj) ? 0.5f : 0.0f);
        }

    float acc = 0.0f;
#pragma unroll 2
    for (int iz = 0; iz < IT; iz++) {
        const int ro = iz * (NPTS / 2);
        const float4 js0 = pjs[ro], js1 = pjs[ro + 1];
        const float4 jt0 = pjt[ro], jt1 = pjt[ro + 1];
        const float4 ks0 = pks[ro], ks1 = pks[ro + 1];
        const float4 kt0 = pkt[ro], kt1 = pkt[ro + 1];

        const float u_sj[4] = {js0.x, js0.z, js1.x, js1.z};
        const float h_sj[4] = {js0.y, js0.w, js1.y, js1.w};
        const float u_tj[4] = {jt0.x, jt0.z, jt1.x, jt1.z};
        const float h_tj[4] = {jt0.y, jt0.w, jt1.y, jt1.w};
        const float u_sk[4] = {ks0.x, ks0.z, ks1.x, ks1.z};
        const float h_sk[4] = {ks0.y, ks0.w, ks1.y, ks1.w};
        const float u_tk[4] = {kt0.x, kt0.z, kt1.x, kt1.z};
        const float h_tk[4] = {kt0.y, kt0.w, kt1.y, kt1.w};

        if (offd) {
#pragma unroll
            for (int a = 0; a < 4; a++) {
                const float usa = u_sj[a], hsa = h_sj[a];
                const float uta = u_tj[a], hta = h_tj[a];
#pragma unroll
                for (int b = 0; b < 4; b++) {
                    const float ts = cs[a][b] + hsa + h_sk[b];
                    const float tt = ct[a][b] + hta + h_tk[b];
                    const float ps = usa * u_sk[b];
                    const float pt = uta * u_tk[b];
                    const float mt = pt * tt;
                    const float d  = fmaf(ps, ts, -mt);
                    const float q  = d * d;
                    const float w  = fmaf(2.0f, fabsf(d), -1.0f);
                    acc += __builtin_amdgcn_fmed3f(q, w, 1.0f);
                }
            }
        } else {
#pragma unroll
            for (int a = 0; a < 4; a++) {
                const float usa = u_sj[a], hsa = h_sj[a];
                const float uta = u_tj[a], hta = h_tj[a];
#pragma unroll
                for (int b = 0; b < 4; b++) {
                    const float ts = cs[a][b] + hsa + h_sk[b];
                    const float tt = ct[a][b] + hta + h_tk[b];
                    const float ps = usa * u_sk[b];
                    const float pt = uta * u_tk[b];
                    const float mt = pt * tt;
                    const float d  = fmaf(ps, ts, -mt);
                    const float q  = d * d;
                    const float w  = fmaf(2.0f, fabsf(d), -1.0f);
                    const float l  = __builtin_amdgcn_fmed3f(q, w, 1.0f);
                    acc = fmaf(wh[a][b], l, acc);
                }
            }
        }
    }

#pragma unroll
    for (int off = 32; off > 0; off >>= 1)
        acc += __shfl_down(acc, off, 64);

    __shared__ float wsum[4];
    const int tid  = ty * 16 + tx;
    const int wid  = tid >> 6;
    const int lane = tid & 63;
    if (lane == 0) wsum[wid] = acc;
    __syncthreads();
    if (tid == 0) {
        const float s = wsum[0] + wsum[1] + wsum[2] + wsum[3];
        atomicAdd(out, s * (1.0f / (384.0f * 384.0f * 384.0f)));
    }
}

extern "C" void kernel_launch(void* const* d_in, const int* in_sizes, int n_in,
                              void* d_out, int out_size, void* d_ws, size_t ws_size,
                              hipStream_t stream) {
    const float* student = (const float*)d_in[0];
    const float* teacher = (const float*)d_in[1];
    float* out = (float*)d_out;

    // ws layout: UHs[NN float2], UHt[NN float2], HDs[NPTS], HDt[NPTS]
    float2* UHs = (float2*)d_ws;
    float2* UHt = UHs + NN;
    float*  HDs = (float*)(UHt + NN);
    float*  HDt = HDs + NPTS;

    gram_fused_kernel<<<dim3(NPTS / 32, NPTS / 32, 2), dim3(16, 16, 4), 0, stream>>>(
        student, teacher, UHs, UHt, HDs, HDt, out);

    rkd_main_kernel<<<dim3(21, NZI), dim3(16, 16), 0, stream>>>(
        UHs, UHt, HDs, HDt, out);
}